// Round 11
// baseline (944.229 us; speedup 1.0000x reference)
//
#include <hip/hip_runtime.h>

// ---------------- types ----------------
typedef float f32x4 __attribute__((ext_vector_type(4)));
typedef __bf16 bf16x8 __attribute__((ext_vector_type(8)));
typedef unsigned short u16x4 __attribute__((ext_vector_type(4)));
typedef unsigned short u16x8 __attribute__((ext_vector_type(8)));

#define HIDDEN 4096
#define NH 32
#define NKV 2
#define HD 128
#define SLEN 2048
#define BATCH 2
#define QKV_OUT 4608  // NH*HD + 2*NKV*HD
#define MROWS 4096    // BATCH*SLEN
#define ATT_SCALE 0.08838834764831845f  // 128^-0.5 (folded into Q at prep)
#define KCHUNK 1024                     // split-K chunk (16 steps of 64)

// fp32 -> bf16 (RNE) bit pattern
__device__ __forceinline__ unsigned short f2bf(float f) {
  unsigned int u = __float_as_uint(f);
  u += 0x7fffu + ((u >> 16) & 1u);
  return (unsigned short)(u >> 16);
}

__device__ __forceinline__ float bf2f(unsigned short s) {
  return __uint_as_float((unsigned int)s << 16);
}

__device__ __forceinline__ void gload16(const void* g, void* l) {
  __builtin_amdgcn_global_load_lds((const __attribute__((address_space(1))) void*)g,
                                   (__attribute__((address_space(3))) void*)l, 16, 0, 0);
}

// ---------------- fp32 -> bf16 convert ----------------
__global__ __launch_bounds__(256) void cvt_f32_bf16(const float* __restrict__ src,
                                                    unsigned short* __restrict__ dst,
                                                    int n4) {
  int stride = gridDim.x * blockDim.x;
  for (int i = blockIdx.x * blockDim.x + threadIdx.x; i < n4; i += stride) {
    float4 v = reinterpret_cast<const float4*>(src)[i];
    u16x4 o;
    o[0] = f2bf(v.x); o[1] = f2bf(v.y); o[2] = f2bf(v.z); o[3] = f2bf(v.w);
    reinterpret_cast<u16x4*>(dst)[i] = o;
  }
}

// ---------------- bf16 MFMA GEMM: C[M][N] = A[M][K] * B[N][K]^T (+bias) ----------------
// m97 128x128 structure, DEFAULT block mapping (r8-exact).
__global__ __launch_bounds__(256) void gemm_bf16_mfma(
    const unsigned short* __restrict__ A, const unsigned short* __restrict__ B,
    const float* __restrict__ bias, void* __restrict__ Cout, int M, int N, int K,
    int c_bf16) {
  __shared__ unsigned short as_[128 * 32];
  __shared__ unsigned short bs_[128 * 32];
  const int tid = threadIdx.x;
  const int wave = tid >> 6;
  const int lane = tid & 63;
  const int m0 = blockIdx.y * 128;
  const int n0 = blockIdx.x * 128;
  const int wm = (wave >> 1) * 64;
  const int wn = (wave & 1) * 64;

  f32x4 acc[4][4] = {};

  const int srow = wave * 32 + (lane >> 2);
  const int scol = (lane & 3) * 8;
  unsigned short* lA = as_ + wave * 1024;
  unsigned short* lB = bs_ + wave * 1024;

  const int nk = K >> 5;
  for (int kt = 0; kt < nk; ++kt) {
    const int kb = kt << 5;
    __syncthreads();
    gload16(A + (size_t)(m0 + srow) * K + kb + scol, lA);
    gload16(A + (size_t)(m0 + srow + 16) * K + kb + scol, lA + 512);
    gload16(B + (size_t)(n0 + srow) * K + kb + scol, lB);
    gload16(B + (size_t)(n0 + srow + 16) * K + kb + scol, lB + 512);
    __syncthreads();

    bf16x8 aF[4], bF[4];
#pragma unroll
    for (int m4 = 0; m4 < 4; ++m4)
      aF[m4] = *reinterpret_cast<const bf16x8*>(
          &as_[(wm + m4 * 16 + (lane & 15)) * 32 + (lane >> 4) * 8]);
#pragma unroll
    for (int n4 = 0; n4 < 4; ++n4)
      bF[n4] = *reinterpret_cast<const bf16x8*>(
          &bs_[(wn + n4 * 16 + (lane & 15)) * 32 + (lane >> 4) * 8]);
#pragma unroll
    for (int m4 = 0; m4 < 4; ++m4)
#pragma unroll
      for (int n4 = 0; n4 < 4; ++n4)
        acc[m4][n4] =
            __builtin_amdgcn_mfma_f32_16x16x32_bf16(aF[m4], bF[n4], acc[m4][n4], 0, 0, 0);
  }

#pragma unroll
  for (int m4 = 0; m4 < 4; ++m4) {
#pragma unroll
    for (int n4 = 0; n4 < 4; ++n4) {
      const int col = n0 + wn + n4 * 16 + (lane & 15);
      const float bv = bias ? bias[col] : 0.0f;
      if (c_bf16) {
        unsigned short* C = (unsigned short*)Cout;
#pragma unroll
        for (int r = 0; r < 4; ++r) {
          const int row = m0 + wm + m4 * 16 + (lane >> 4) * 4 + r;
          C[(size_t)row * N + col] = f2bf(acc[m4][n4][r] + bv);
        }
      } else {
        float* C = (float*)Cout;
#pragma unroll
        for (int r = 0; r < 4; ++r) {
          const int row = m0 + wm + m4 * 16 + (lane >> 4) * 4 + r;
          C[(size_t)row * N + col] = acc[m4][n4][r] + bv;
        }
      }
    }
  }
}

// ---------------- prep: RoPE (fp32 trig) on bf16 mixed + scale-fold + head-major ----------------
__global__ __launch_bounds__(256) void prep_qkv(const unsigned short* __restrict__ mixed,
                                                const int* __restrict__ positions,
                                                unsigned short* __restrict__ Qb,
                                                unsigned short* __restrict__ Kb,
                                                unsigned short* __restrict__ Vt) {
  const int m = blockIdx.x;
  const int b = m >> 11, s = m & 2047;
  const float pos = (float)positions[m];
  const int dp = threadIdx.x & 63;  // pair index within head (d = 2*dp)
  const bool rope_lane = (dp < 32);
  float sn = 0.0f, cs = 1.0f;
  if (rope_lane) {
    const float inv = __expf(-(float)dp * 0.28782313662425572f);  // 10000^(-dp/32)
    sincosf(pos * inv, &sn, &cs);
  }
  const unsigned int* row =
      reinterpret_cast<const unsigned int*>(mixed + (size_t)m * QKV_OUT);
#pragma unroll
  for (int it = 0; it < 9; ++it) {
    const int p = it * 256 + threadIdx.x;  // pair index, 2304 total
    const int col = p * 2;
    const unsigned int pk = row[p];
    float r1 = bf2f((unsigned short)(pk & 0xffffu));
    float r2 = bf2f((unsigned short)(pk >> 16));
    const int d = col & 127;
    const bool is_v = (col >= NH * HD + NKV * HD);
    if (rope_lane && !is_v) {
      const float x1 = r1, x2 = r2;
      r1 = x1 * cs - x2 * sn;
      r2 = x1 * sn + x2 * cs;
    }
    if (col < NH * HD) {  // q: fold attention scale
      r1 *= ATT_SCALE;
      r2 *= ATT_SCALE;
      const int h = col >> 7;
      const unsigned int packed = (unsigned int)f2bf(r1) | ((unsigned int)f2bf(r2) << 16);
      *reinterpret_cast<unsigned int*>(
          &Qb[((size_t)(b * NH + h) * SLEN + s) * HD + d]) = packed;
    } else if (!is_v) {
      const int kv = (col - NH * HD) >> 7;
      const unsigned int packed = (unsigned int)f2bf(r1) | ((unsigned int)f2bf(r2) << 16);
      *reinterpret_cast<unsigned int*>(
          &Kb[((size_t)(b * NKV + kv) * SLEN + s) * HD + d]) = packed;
    } else {
      const int kv = (col - NH * HD - NKV * HD) >> 7;
      unsigned short* vb = Vt + ((size_t)(b * NKV + kv) * HD) * SLEN + s;
      vb[(size_t)d * SLEN] = f2bf(r1);
      vb[(size_t)(d + 1) * SLEN] = f2bf(r2);
    }
  }
}

// ---------------- bf16 MFMA flash attention v9: direct-from-L2 K/V, zero barriers ----------------
// K/V per (b,kv) = 1MB; all 4 combos fit one XCD L2 (4MB) -> LDS staging was pure
// overhead (guide m168->m169). K and V^T fragments are read 16B/lane straight from
// global into MFMA registers. Only P remains in LDS (wave-private, same-wave
// write->read needs no barrier: proven in r10). NO __syncthreads anywhere in the
// loop; waves free-run, causal-tail imbalance self-smooths. LDS 16KB.
__global__ __launch_bounds__(256) void flash_mfma(const unsigned short* __restrict__ Qb,
                                                  const unsigned short* __restrict__ Kb,
                                                  const unsigned short* __restrict__ Vt,
                                                  unsigned short* __restrict__ ctx,
                                                  unsigned short* __restrict__ Om,
                                                  float* __restrict__ Ml) {
  __shared__ unsigned short Ps[4][32 * 64];  // wave-private P, 16KB total

  const int tid = threadIdx.x;
  const int wave = tid >> 6, lane = tid & 63;
  const int lr = lane & 15, lg = lane >> 4;

  // decode (qt, chunk), heavy blocks first
  const int i = blockIdx.x;
  int qt, c;
  if (i < 8) { qt = 15 - i; c = 0; }            // qt 15..8, chunk 0 (16 steps)
  else if (i < 16) { qt = 23 - i; c = 1; }      // qt 15..8, chunk 1
  else { qt = 23 - i; c = 0; }                  // qt 7..0, single chunk
  const int h = blockIdx.y, b = blockIdx.z;
  const int kv = h >> 4;  // G = 16
  const int q0 = qt * 128;
  const int s_begin = c * KCHUNK;
  const int s_end = min(KCHUNK * (c + 1), q0 + 128);
  const int nkt = (s_end - s_begin) >> 6;
  const bool single = (c == 0) && (s_end == q0 + 128);
  const int qbw = q0 + wave * 32;  // this wave's first q row

  // per-wave step bound: steps with s0 >= qbw+32 are non-participating -> skip
  const int nkt_w = min(nkt, (qbw + 32 - s_begin + 63) >> 6);

  const unsigned short* Kbase = Kb + (size_t)(b * NKV + kv) * SLEN * HD;
  const unsigned short* Vbase = Vt + (size_t)(b * NKV + kv) * HD * SLEN;

  // Q B-fragments (col = q = lr within 16-group, k = lg*8 + ks*32); pre-scaled
  bf16x8 bQ[2][4];
#pragma unroll
  for (int qg = 0; qg < 2; ++qg) {
    const unsigned short* qp =
        Qb + ((size_t)(b * NH + h) * SLEN + qbw + qg * 16 + lr) * HD;
#pragma unroll
    for (int ks = 0; ks < 4; ++ks)
      bQ[qg][ks] = *reinterpret_cast<const bf16x8*>(qp + lg * 8 + ks * 32);
  }

  f32x4 accO[2][8] = {};
  float mi[2] = {-1e30f, -1e30f}, li[2] = {0.0f, 0.0f};

  unsigned short* Pw = Ps[wave];  // wave-private

  for (int kt = 0; kt < nkt_w; ++kt) {
    const int s0 = s_begin + kt * 64;

    // ---- S^T = K·Q^T : aK direct from L2 (16B/lane, contiguous) ----
    bf16x8 aK[4][4];
#pragma unroll
    for (int kb = 0; kb < 4; ++kb) {
      const unsigned short* kr = Kbase + (size_t)(s0 + kb * 16 + lr) * HD + lg * 8;
#pragma unroll
      for (int ks = 0; ks < 4; ++ks)
        aK[kb][ks] = *reinterpret_cast<const bf16x8*>(kr + ks * 32);
    }
    f32x4 accS[2][4] = {};
#pragma unroll
    for (int kb = 0; kb < 4; ++kb) {
#pragma unroll
      for (int ks = 0; ks < 4; ++ks) {
        accS[0][kb] = __builtin_amdgcn_mfma_f32_16x16x32_bf16(aK[kb][ks], bQ[0][ks], accS[0][kb], 0, 0, 0);
        accS[1][kb] = __builtin_amdgcn_mfma_f32_16x16x32_bf16(aK[kb][ks], bQ[1][ks], accS[1][kb], 0, 0, 0);
      }
    }

    // ---- lane-local online softmax ----
#pragma unroll
    for (int qg = 0; qg < 2; ++qg) {
      const int qrow = qbw + qg * 16 + lr;
      float v[16];
#pragma unroll
      for (int kb = 0; kb < 4; ++kb)
#pragma unroll
        for (int r = 0; r < 4; ++r) v[kb * 4 + r] = accS[qg][kb][r];
      if (s0 + 63 > qbw + qg * 16) {  // mask if last key can exceed group's FIRST row
#pragma unroll
        for (int kb = 0; kb < 4; ++kb)
#pragma unroll
          for (int r = 0; r < 4; ++r)
            if (s0 + kb * 16 + lg * 4 + r > qrow) v[kb * 4 + r] = -1e30f;
      }
      float m16 = v[0];
#pragma unroll
      for (int i2 = 1; i2 < 16; ++i2) m16 = fmaxf(m16, v[i2]);
      m16 = fmaxf(m16, __shfl_xor(m16, 16));
      m16 = fmaxf(m16, __shfl_xor(m16, 32));
      const float mnew = fmaxf(mi[qg], m16);
      const float cf = __expf(mi[qg] - mnew);
      mi[qg] = mnew;
      float rs = 0.0f;
#pragma unroll
      for (int i2 = 0; i2 < 16; ++i2) {
        const float p = __expf(v[i2] - mnew);
        v[i2] = p;
        rs += p;
      }
      rs += __shfl_xor(rs, 16);
      rs += __shfl_xor(rs, 32);
      li[qg] = li[qg] * cf + rs;
#pragma unroll
      for (int n8 = 0; n8 < 8; ++n8) accO[qg][n8] *= cf;
#pragma unroll
      for (int kb = 0; kb < 4; ++kb) {
        const int slot = (kb * 2 + (lg >> 1)) ^ (lr & 7);
        u16x4 pk;
        pk[0] = f2bf(v[kb * 4 + 0]); pk[1] = f2bf(v[kb * 4 + 1]);
        pk[2] = f2bf(v[kb * 4 + 2]); pk[3] = f2bf(v[kb * 4 + 3]);
        *reinterpret_cast<u16x4*>(
            &Pw[(qg * 16 + lr) * 64 + slot * 8 + (lg & 1) * 4]) = pk;
      }
    }

    // ---- O^T += V^T · P^T : aV direct from L2 ----
    bf16x8 pa[2][2];
#pragma unroll
    for (int qg = 0; qg < 2; ++qg)
#pragma unroll
      for (int ks = 0; ks < 2; ++ks)
        pa[qg][ks] = *reinterpret_cast<const bf16x8*>(
            &Pw[(qg * 16 + lr) * 64 + (((ks * 4 + lg) ^ (lr & 7)) << 3)]);
#pragma unroll
    for (int ks = 0; ks < 2; ++ks) {
#pragma unroll
      for (int n8 = 0; n8 < 8; ++n8) {
        bf16x8 aV = *reinterpret_cast<const bf16x8*>(
            Vbase + (size_t)(n8 * 16 + lr) * SLEN + s0 + ks * 32 + lg * 8);
        accO[0][n8] = __builtin_amdgcn_mfma_f32_16x16x32_bf16(aV, pa[0][ks], accO[0][n8], 0, 0, 0);
        accO[1][n8] = __builtin_amdgcn_mfma_f32_16x16x32_bf16(aV, pa[1][ks], accO[1][n8], 0, 0, 0);
      }
    }
  }

  if (single) {
#pragma unroll
    for (int qg = 0; qg < 2; ++qg) {
      const float inv = 1.0f / li[qg];
      unsigned short* orow =
          ctx + (size_t)(b * SLEN + qbw + qg * 16 + lr) * HIDDEN + h * HD + lg * 4;
#pragma unroll
      for (int n8 = 0; n8 < 8; ++n8) {
        u16x4 o;
#pragma unroll
        for (int r = 0; r < 4; ++r) o[r] = f2bf(accO[qg][n8][r] * inv);
        *reinterpret_cast<u16x4*>(orow + n8 * 16) = o;
      }
    }
  } else {
#pragma unroll
    for (int qg = 0; qg < 2; ++qg) {
      const int row1k = qbw + qg * 16 + lr - 1024;
      const size_t pbase = (size_t)((b * NH + h) * 2 + c) * 1024 + row1k;
      if (lg == 0) {
        Ml[pbase * 2] = mi[qg];
        Ml[pbase * 2 + 1] = li[qg];
      }
      unsigned short* prow = Om + pbase * 128 + lg * 4;
#pragma unroll
      for (int n8 = 0; n8 < 8; ++n8) {
        u16x4 o;
#pragma unroll
        for (int r = 0; r < 4; ++r) o[r] = f2bf(accO[qg][n8][r]);
        *reinterpret_cast<u16x4*>(prow + n8 * 16) = o;
      }
    }
  }
}

// ---------------- combine the two split-K partials (rows 1024..2047 per (b,h)) ----------------
__global__ __launch_bounds__(256) void combine_partials(
    const unsigned short* __restrict__ Om, const float* __restrict__ Ml,
    unsigned short* __restrict__ ctx) {
  const int g = blockIdx.x * 64 + (threadIdx.x >> 2);  // row id, 0..65535
  const int p = threadIdx.x & 3;                       // dim quarter (32 dims)
  const int row1k = g & 1023;
  const int h = (g >> 10) & 31;
  const int b = g >> 15;
  const size_t base0 = (size_t)((b * NH + h) * 2 + 0) * 1024 + row1k;
  const size_t base1 = (size_t)((b * NH + h) * 2 + 1) * 1024 + row1k;
  const float m0 = Ml[base0 * 2], l0 = Ml[base0 * 2 + 1];
  const float m1 = Ml[base1 * 2], l1 = Ml[base1 * 2 + 1];
  const float mx = fmaxf(m0, m1);
  const float w0 = __expf(m0 - mx), w1 = __expf(m1 - mx);
  const float inv = 1.0f / (w0 * l0 + w1 * l1);
  const unsigned short* n0 = Om + base0 * 128 + p * 32;
  const unsigned short* n1 = Om + base1 * 128 + p * 32;
  unsigned short* orow =
      ctx + (size_t)(b * SLEN + 1024 + row1k) * HIDDEN + h * HD + p * 32;
#pragma unroll
  for (int cch = 0; cch < 4; ++cch) {
    u16x8 a = *reinterpret_cast<const u16x8*>(n0 + cch * 8);
    u16x8 d = *reinterpret_cast<const u16x8*>(n1 + cch * 8);
    u16x8 o;
#pragma unroll
    for (int j = 0; j < 8; ++j)
      o[j] = f2bf((w0 * bf2f(a[j]) + w1 * bf2f(d[j])) * inv);
    *reinterpret_cast<u16x8*>(orow + cch * 8) = o;
  }
}

// ---------------- launch ----------------
extern "C" void kernel_launch(void* const* d_in, const int* in_sizes, int n_in,
                              void* d_out, int out_size, void* d_ws, size_t ws_size,
                              hipStream_t stream) {
  const int* positions = (const int*)d_in[0];
  const float* hidden = (const float*)d_in[1];
  const float* w_qkv = (const float*)d_in[2];
  const float* b_qkv = (const float*)d_in[3];
  const float* w_dense = (const float*)d_in[4];
  float* out = (float*)d_out;

  char* ws = (char*)d_ws;
  size_t off = 0;
  unsigned short* mixed = (unsigned short*)(ws + off);  // bf16
  off += (size_t)MROWS * QKV_OUT * 4;  // region kept 75.5 MB (bf16 uses first 37.7)
  unsigned short* h_bf = (unsigned short*)(ws + off);
  off += (size_t)MROWS * HIDDEN * 2;  // 33.6 MB (reused as Qb after QKV GEMM)
  unsigned short* wq_bf = (unsigned short*)(ws + off);
  off += (size_t)QKV_OUT * HIDDEN * 2;  // 37.7 MB (reused as Om after QKV GEMM)
  unsigned short* wd_bf = (unsigned short*)(ws + off);
  off += (size_t)HIDDEN * HIDDEN * 2;  // 33.6 MB
  unsigned short* Kb = (unsigned short*)(ws + off);
  off += (size_t)BATCH * NKV * SLEN * HD * 2;  // 2 MB
  unsigned short* Vt = (unsigned short*)(ws + off);
  off += (size_t)BATCH * NKV * SLEN * HD * 2;  // 2 MB
  unsigned short* Qb = h_bf;                        // alias: h_bf dead after QKV GEMM
  unsigned short* ctx_bf = mixed;                   // alias: mixed dead after prep
  unsigned short* Om = wq_bf;                       // alias: wq_bf dead after QKV GEMM
  float* Ml = (float*)((char*)mixed + 36 * 1024 * 1024);  // mixed-region tail, past ctx_bf

  cvt_f32_bf16<<<2048, 256, 0, stream>>>(hidden, h_bf, MROWS * HIDDEN / 4);
  cvt_f32_bf16<<<2048, 256, 0, stream>>>(w_qkv, wq_bf, QKV_OUT * HIDDEN / 4);
  cvt_f32_bf16<<<2048, 256, 0, stream>>>(w_dense, wd_bf, HIDDEN * HIDDEN / 4);

  gemm_bf16_mfma<<<dim3(QKV_OUT / 128, MROWS / 128), 256, 0, stream>>>(
      h_bf, wq_bf, b_qkv, mixed, MROWS, QKV_OUT, HIDDEN, 1);

  prep_qkv<<<MROWS, 256, 0, stream>>>(mixed, positions, Qb, Kb, Vt);

  flash_mfma<<<dim3(24, NH, BATCH), 256, 0, stream>>>(Qb, Kb, Vt, ctx_bf, Om, Ml);

  combine_partials<<<1024, 256, 0, stream>>>(Om, Ml, ctx_bf);

  gemm_bf16_mfma<<<dim3(HIDDEN / 128, MROWS / 128), 256, 0, stream>>>(
      ctx_bf, wd_bf, nullptr, out, MROWS, HIDDEN, HIDDEN, 0);
}

// Round 12
// 641.280 us; speedup vs baseline: 1.4724x; 1.4724x over previous
//
#include <hip/hip_runtime.h>

// ---------------- types ----------------
typedef float f32x4 __attribute__((ext_vector_type(4)));
typedef __bf16 bf16x8 __attribute__((ext_vector_type(8)));
typedef unsigned short u16x4 __attribute__((ext_vector_type(4)));
typedef unsigned short u16x8 __attribute__((ext_vector_type(8)));

#define HIDDEN 4096
#define NH 32
#define NKV 2
#define HD 128
#define SLEN 2048
#define BATCH 2
#define QKV_OUT 4608  // NH*HD + 2*NKV*HD
#define MROWS 4096    // BATCH*SLEN
#define ATT_SCALE 0.08838834764831845f  // 128^-0.5 (folded into Q at prep)
#define KCHUNK 1024                     // split-K chunk (16 steps of 64)

// fp32 -> bf16 (RNE) bit pattern
__device__ __forceinline__ unsigned short f2bf(float f) {
  unsigned int u = __float_as_uint(f);
  u += 0x7fffu + ((u >> 16) & 1u);
  return (unsigned short)(u >> 16);
}

__device__ __forceinline__ float bf2f(unsigned short s) {
  return __uint_as_float((unsigned int)s << 16);
}

__device__ __forceinline__ void gload16(const void* g, void* l) {
  __builtin_amdgcn_global_load_lds((const __attribute__((address_space(1))) void*)g,
                                   (__attribute__((address_space(3))) void*)l, 16, 0, 0);
}

// ---------------- fp32 -> bf16 convert (3 buffers fused, one launch) ----------------
__global__ __launch_bounds__(256) void cvt3_f32_bf16(
    const float* __restrict__ s0, unsigned short* __restrict__ d0, int n0,
    const float* __restrict__ s1, unsigned short* __restrict__ d1, int n1,
    const float* __restrict__ s2, unsigned short* __restrict__ d2, int n2) {
  const int ntot = n0 + n1 + n2;
  const int stride = gridDim.x * blockDim.x;
  for (int i = blockIdx.x * blockDim.x + threadIdx.x; i < ntot; i += stride) {
    const float* src;
    unsigned short* dst;
    int j = i;
    if (j < n0) { src = s0; dst = d0; }
    else if (j < n0 + n1) { j -= n0; src = s1; dst = d1; }
    else { j -= n0 + n1; src = s2; dst = d2; }
    float4 v = reinterpret_cast<const float4*>(src)[j];
    u16x4 o;
    o[0] = f2bf(v.x); o[1] = f2bf(v.y); o[2] = f2bf(v.z); o[3] = f2bf(v.w);
    reinterpret_cast<u16x4*>(dst)[j] = o;
  }
}

// ---------------- bf16 MFMA GEMM: C[M][N] = A[M][K] * B[N][K]^T (+bias) ----------------
// m97 128x128 structure, DEFAULT block mapping (r8-exact).
__global__ __launch_bounds__(256) void gemm_bf16_mfma(
    const unsigned short* __restrict__ A, const unsigned short* __restrict__ B,
    const float* __restrict__ bias, void* __restrict__ Cout, int M, int N, int K,
    int c_bf16) {
  __shared__ unsigned short as_[128 * 32];
  __shared__ unsigned short bs_[128 * 32];
  const int tid = threadIdx.x;
  const int wave = tid >> 6;
  const int lane = tid & 63;
  const int m0 = blockIdx.y * 128;
  const int n0 = blockIdx.x * 128;
  const int wm = (wave >> 1) * 64;
  const int wn = (wave & 1) * 64;

  f32x4 acc[4][4] = {};

  const int srow = wave * 32 + (lane >> 2);
  const int scol = (lane & 3) * 8;
  unsigned short* lA = as_ + wave * 1024;
  unsigned short* lB = bs_ + wave * 1024;

  const int nk = K >> 5;
  for (int kt = 0; kt < nk; ++kt) {
    const int kb = kt << 5;
    __syncthreads();
    gload16(A + (size_t)(m0 + srow) * K + kb + scol, lA);
    gload16(A + (size_t)(m0 + srow + 16) * K + kb + scol, lA + 512);
    gload16(B + (size_t)(n0 + srow) * K + kb + scol, lB);
    gload16(B + (size_t)(n0 + srow + 16) * K + kb + scol, lB + 512);
    __syncthreads();

    bf16x8 aF[4], bF[4];
#pragma unroll
    for (int m4 = 0; m4 < 4; ++m4)
      aF[m4] = *reinterpret_cast<const bf16x8*>(
          &as_[(wm + m4 * 16 + (lane & 15)) * 32 + (lane >> 4) * 8]);
#pragma unroll
    for (int n4 = 0; n4 < 4; ++n4)
      bF[n4] = *reinterpret_cast<const bf16x8*>(
          &bs_[(wn + n4 * 16 + (lane & 15)) * 32 + (lane >> 4) * 8]);
#pragma unroll
    for (int m4 = 0; m4 < 4; ++m4)
#pragma unroll
      for (int n4 = 0; n4 < 4; ++n4)
        acc[m4][n4] =
            __builtin_amdgcn_mfma_f32_16x16x32_bf16(aF[m4], bF[n4], acc[m4][n4], 0, 0, 0);
  }

#pragma unroll
  for (int m4 = 0; m4 < 4; ++m4) {
#pragma unroll
    for (int n4 = 0; n4 < 4; ++n4) {
      const int col = n0 + wn + n4 * 16 + (lane & 15);
      const float bv = bias ? bias[col] : 0.0f;
      if (c_bf16) {
        unsigned short* C = (unsigned short*)Cout;
#pragma unroll
        for (int r = 0; r < 4; ++r) {
          const int row = m0 + wm + m4 * 16 + (lane >> 4) * 4 + r;
          C[(size_t)row * N + col] = f2bf(acc[m4][n4][r] + bv);
        }
      } else {
        float* C = (float*)Cout;
#pragma unroll
        for (int r = 0; r < 4; ++r) {
          const int row = m0 + wm + m4 * 16 + (lane >> 4) * 4 + r;
          C[(size_t)row * N + col] = acc[m4][n4][r] + bv;
        }
      }
    }
  }
}

// ---------------- prep: RoPE (fp32 trig) on bf16 mixed + scale-fold + head-major ----------------
__global__ __launch_bounds__(256) void prep_qkv(const unsigned short* __restrict__ mixed,
                                                const int* __restrict__ positions,
                                                unsigned short* __restrict__ Qb,
                                                unsigned short* __restrict__ Kb,
                                                unsigned short* __restrict__ Vt) {
  const int m = blockIdx.x;
  const int b = m >> 11, s = m & 2047;
  const float pos = (float)positions[m];
  const int dp = threadIdx.x & 63;  // pair index within head (d = 2*dp)
  const bool rope_lane = (dp < 32);
  float sn = 0.0f, cs = 1.0f;
  if (rope_lane) {
    const float inv = __expf(-(float)dp * 0.28782313662425572f);  // 10000^(-dp/32)
    sincosf(pos * inv, &sn, &cs);
  }
  const unsigned int* row =
      reinterpret_cast<const unsigned int*>(mixed + (size_t)m * QKV_OUT);
#pragma unroll
  for (int it = 0; it < 9; ++it) {
    const int p = it * 256 + threadIdx.x;  // pair index, 2304 total
    const int col = p * 2;
    const unsigned int pk = row[p];
    float r1 = bf2f((unsigned short)(pk & 0xffffu));
    float r2 = bf2f((unsigned short)(pk >> 16));
    const int d = col & 127;
    const bool is_v = (col >= NH * HD + NKV * HD);
    if (rope_lane && !is_v) {
      const float x1 = r1, x2 = r2;
      r1 = x1 * cs - x2 * sn;
      r2 = x1 * sn + x2 * cs;
    }
    if (col < NH * HD) {  // q: fold attention scale
      r1 *= ATT_SCALE;
      r2 *= ATT_SCALE;
      const int h = col >> 7;
      const unsigned int packed = (unsigned int)f2bf(r1) | ((unsigned int)f2bf(r2) << 16);
      *reinterpret_cast<unsigned int*>(
          &Qb[((size_t)(b * NH + h) * SLEN + s) * HD + d]) = packed;
    } else if (!is_v) {
      const int kv = (col - NH * HD) >> 7;
      const unsigned int packed = (unsigned int)f2bf(r1) | ((unsigned int)f2bf(r2) << 16);
      *reinterpret_cast<unsigned int*>(
          &Kb[((size_t)(b * NKV + kv) * SLEN + s) * HD + d]) = packed;
    } else {
      const int kv = (col - NH * HD - NKV * HD) >> 7;
      unsigned short* vb = Vt + ((size_t)(b * NKV + kv) * HD) * SLEN + s;
      vb[(size_t)d * SLEN] = f2bf(r1);
      vb[(size_t)(d + 1) * SLEN] = f2bf(r2);
    }
  }
}

// ---------------- bf16 MFMA flash attention v10: 8 waves x 16 q ----------------
// Same microtile math as r5 with the qg dimension removed: per-wave state halves
// (acc 64->32 VGPR etc.) so fragment loads can batch, and LDS=64KB gives 2 blocks/CU
// = 4 waves/SIMD (2x the 4-wave kernel's TLP). Proven r5 2-barrier schedule; P is
// wave-private (r10-verified: same-wave LDS write->read needs no barrier).
__global__ __launch_bounds__(512) void flash_mfma(const unsigned short* __restrict__ Qb,
                                                  const unsigned short* __restrict__ Kb,
                                                  const unsigned short* __restrict__ Vt,
                                                  unsigned short* __restrict__ ctx,
                                                  unsigned short* __restrict__ Om,
                                                  float* __restrict__ Ml) {
  __shared__ unsigned short Ks[2][64 * 128];  // [key][d] swizzled, 2x16KB
  __shared__ unsigned short Vs[128 * 64];     // [d][key] swizzled, 16KB
  __shared__ unsigned short Ps[8][16 * 64];   // wave-private P, 8x2KB

  const int tid = threadIdx.x;
  const int wave = tid >> 6, lane = tid & 63;
  const int lr = lane & 15, lg = lane >> 4;

  // decode (qt, chunk), heavy blocks first
  const int i = blockIdx.x;
  int qt, c;
  if (i < 8) { qt = 15 - i; c = 0; }            // qt 15..8, chunk 0 (16 steps)
  else if (i < 16) { qt = 23 - i; c = 1; }      // qt 15..8, chunk 1
  else { qt = 23 - i; c = 0; }                  // qt 7..0, single chunk
  const int h = blockIdx.y, b = blockIdx.z;
  const int kv = h >> 4;  // G = 16
  const int q0 = qt * 128;
  const int s_begin = c * KCHUNK;
  const int s_end = min(KCHUNK * (c + 1), q0 + 128);
  const int nkt = (s_end - s_begin) >> 6;
  const bool single = (c == 0) && (s_end == q0 + 128);
  const int qbw = q0 + wave * 16;  // this wave's first (and only) 16-q group

  const unsigned short* Kbase = Kb + (size_t)(b * NKV + kv) * SLEN * HD;
  const unsigned short* Vbase = Vt + (size_t)(b * NKV + kv) * HD * SLEN;

  // Q B-fragments (col = q = lr, k = lg*8 + ks*32); pre-scaled
  bf16x8 bQ[4];
  {
    const unsigned short* qp =
        Qb + ((size_t)(b * NH + h) * SLEN + qbw + lr) * HD;
#pragma unroll
    for (int ks = 0; ks < 4; ++ks)
      bQ[ks] = *reinterpret_cast<const bf16x8*>(qp + lg * 8 + ks * 32);
  }

  f32x4 accO[8] = {};
  float mi = -1e30f, li = 0.0f;

  const int vrow_off = lane >> 3, vchunk = lane & 7;
#define STAGE_K(cb, t)                                                                  \
  {                                                                                     \
    const int ss = s_begin + (t) * 64;                                                  \
    _Pragma("unroll") for (int si = 0; si < 2; ++si) {                                  \
      const int krow = wave * 8 + si * 4 + lg;                                          \
      gload16(Kbase + (size_t)(ss + krow) * HD + ((lr ^ (krow & 7)) << 3),              \
              &Ks[cb][(wave * 8 + si * 4) * 128]);                                      \
    }                                                                                   \
  }
#define STAGE_V(t)                                                                      \
  {                                                                                     \
    const int ss = s_begin + (t) * 64;                                                  \
    _Pragma("unroll") for (int si = 0; si < 2; ++si) {                                  \
      const int drow = wave * 16 + si * 8 + vrow_off;                                   \
      gload16(Vbase + (size_t)drow * SLEN + ss + ((vchunk ^ (drow & 7)) << 3),          \
              &Vs[(wave * 16 + si * 8) * 64]);                                          \
    }                                                                                   \
  }

  STAGE_K(0, 0);
  __syncthreads();  // K0 ready

  unsigned short* Pw = Ps[wave];

  for (int kt = 0; kt < nkt; ++kt) {
    const int cur = kt & 1;
    const int s0 = s_begin + kt * 64;
    STAGE_V(kt);                                 // V for THIS step (ready at mid barrier)
    if (kt + 1 < nkt) STAGE_K(cur ^ 1, kt + 1);  // K prefetch for next step
    const bool part = (s0 < qbw + 16);

    f32x4 accS[4] = {};
    if (part) {
      // batch all K fragments first (fits now: 64 VGPR), then MFMA
      bf16x8 aK[4][4];
#pragma unroll
      for (int kb = 0; kb < 4; ++kb)
#pragma unroll
        for (int ks = 0; ks < 4; ++ks)
          aK[kb][ks] = *reinterpret_cast<const bf16x8*>(
              &Ks[cur][(kb * 16 + lr) * 128 + (((ks * 4 + lg) ^ (lr & 7)) << 3)]);
#pragma unroll
      for (int kb = 0; kb < 4; ++kb)
#pragma unroll
        for (int ks = 0; ks < 4; ++ks)
          accS[kb] = __builtin_amdgcn_mfma_f32_16x16x32_bf16(aK[kb][ks], bQ[ks], accS[kb], 0, 0, 0);
    }

    __syncthreads();  // mid: V staged + QK reads of Ks[cur] done across waves

    if (part) {
      // ---- lane-local online softmax (one q per lane) ----
      const int qrow = qbw + lr;
      float v[16];
#pragma unroll
      for (int kb = 0; kb < 4; ++kb)
#pragma unroll
        for (int r = 0; r < 4; ++r) v[kb * 4 + r] = accS[kb][r];
      if (s0 + 63 > qbw) {  // mask if last key can exceed group's FIRST row
#pragma unroll
        for (int kb = 0; kb < 4; ++kb)
#pragma unroll
          for (int r = 0; r < 4; ++r)
            if (s0 + kb * 16 + lg * 4 + r > qrow) v[kb * 4 + r] = -1e30f;
      }
      float m16 = v[0];
#pragma unroll
      for (int i2 = 1; i2 < 16; ++i2) m16 = fmaxf(m16, v[i2]);
      m16 = fmaxf(m16, __shfl_xor(m16, 16));
      m16 = fmaxf(m16, __shfl_xor(m16, 32));
      const float mnew = fmaxf(mi, m16);
      const float cf = __expf(mi - mnew);
      mi = mnew;
      float rs = 0.0f;
#pragma unroll
      for (int i2 = 0; i2 < 16; ++i2) {
        const float p = __expf(v[i2] - mnew);
        v[i2] = p;
        rs += p;
      }
      rs += __shfl_xor(rs, 16);
      rs += __shfl_xor(rs, 32);
      li = li * cf + rs;
#pragma unroll
      for (int n8 = 0; n8 < 8; ++n8) accO[n8] *= cf;
#pragma unroll
      for (int kb = 0; kb < 4; ++kb) {
        const int slot = (kb * 2 + (lg >> 1)) ^ (lr & 7);
        u16x4 pk;
        pk[0] = f2bf(v[kb * 4 + 0]); pk[1] = f2bf(v[kb * 4 + 1]);
        pk[2] = f2bf(v[kb * 4 + 2]); pk[3] = f2bf(v[kb * 4 + 3]);
        *reinterpret_cast<u16x4*>(&Pw[lr * 64 + slot * 8 + (lg & 1) * 4]) = pk;
      }

      // ---- O^T += V^T · P^T ----
      bf16x8 pa[2];
#pragma unroll
      for (int ks = 0; ks < 2; ++ks)
        pa[ks] = *reinterpret_cast<const bf16x8*>(
            &Pw[lr * 64 + (((ks * 4 + lg) ^ (lr & 7)) << 3)]);
#pragma unroll
      for (int ks = 0; ks < 2; ++ks) {
#pragma unroll
        for (int n8 = 0; n8 < 8; ++n8) {
          bf16x8 aV = *reinterpret_cast<const bf16x8*>(
              &Vs[(n8 * 16 + lr) * 64 + (((ks * 4 + lg) ^ (lr & 7)) << 3)]);
          accO[n8] = __builtin_amdgcn_mfma_f32_16x16x32_bf16(aV, pa[ks], accO[n8], 0, 0, 0);
        }
      }
    }

    __syncthreads();  // bottom: drains prefetch; orders Vs/Ks reuse
  }
#undef STAGE_K
#undef STAGE_V

  if (single) {
    const float inv = 1.0f / li;
    unsigned short* orow =
        ctx + (size_t)(b * SLEN + qbw + lr) * HIDDEN + h * HD + lg * 4;
#pragma unroll
    for (int n8 = 0; n8 < 8; ++n8) {
      u16x4 o;
#pragma unroll
      for (int r = 0; r < 4; ++r) o[r] = f2bf(accO[n8][r] * inv);
      *reinterpret_cast<u16x4*>(orow + n8 * 16) = o;
    }
  } else {
    const int row1k = qbw + lr - 1024;
    const size_t pbase = (size_t)((b * NH + h) * 2 + c) * 1024 + row1k;
    if (lg == 0) {
      Ml[pbase * 2] = mi;
      Ml[pbase * 2 + 1] = li;
    }
    unsigned short* prow = Om + pbase * 128 + lg * 4;
#pragma unroll
    for (int n8 = 0; n8 < 8; ++n8) {
      u16x4 o;
#pragma unroll
      for (int r = 0; r < 4; ++r) o[r] = f2bf(accO[n8][r]);
      *reinterpret_cast<u16x4*>(prow + n8 * 16) = o;
    }
  }
}

// ---------------- combine the two split-K partials (rows 1024..2047 per (b,h)) ----------------
__global__ __launch_bounds__(256) void combine_partials(
    const unsigned short* __restrict__ Om, const float* __restrict__ Ml,
    unsigned short* __restrict__ ctx) {
  const int g = blockIdx.x * 64 + (threadIdx.x >> 2);  // row id, 0..65535
  const int p = threadIdx.x & 3;                       // dim quarter (32 dims)
  const int row1k = g & 1023;
  const int h = (g >> 10) & 31;
  const int b = g >> 15;
  const size_t base0 = (size_t)((b * NH + h) * 2 + 0) * 1024 + row1k;
  const size_t base1 = (size_t)((b * NH + h) * 2 + 1) * 1024 + row1k;
  const float m0 = Ml[base0 * 2], l0 = Ml[base0 * 2 + 1];
  const float m1 = Ml[base1 * 2], l1 = Ml[base1 * 2 + 1];
  const float mx = fmaxf(m0, m1);
  const float w0 = __expf(m0 - mx), w1 = __expf(m1 - mx);
  const float inv = 1.0f / (w0 * l0 + w1 * l1);
  const unsigned short* n0 = Om + base0 * 128 + p * 32;
  const unsigned short* n1 = Om + base1 * 128 + p * 32;
  unsigned short* orow =
      ctx + (size_t)(b * SLEN + 1024 + row1k) * HIDDEN + h * HD + p * 32;
#pragma unroll
  for (int cch = 0; cch < 4; ++cch) {
    u16x8 a = *reinterpret_cast<const u16x8*>(n0 + cch * 8);
    u16x8 d = *reinterpret_cast<const u16x8*>(n1 + cch * 8);
    u16x8 o;
#pragma unroll
    for (int j = 0; j < 8; ++j)
      o[j] = f2bf((w0 * bf2f(a[j]) + w1 * bf2f(d[j])) * inv);
    *reinterpret_cast<u16x8*>(orow + cch * 8) = o;
  }
}

// ---------------- launch ----------------
extern "C" void kernel_launch(void* const* d_in, const int* in_sizes, int n_in,
                              void* d_out, int out_size, void* d_ws, size_t ws_size,
                              hipStream_t stream) {
  const int* positions = (const int*)d_in[0];
  const float* hidden = (const float*)d_in[1];
  const float* w_qkv = (const float*)d_in[2];
  const float* b_qkv = (const float*)d_in[3];
  const float* w_dense = (const float*)d_in[4];
  float* out = (float*)d_out;

  char* ws = (char*)d_ws;
  size_t off = 0;
  unsigned short* mixed = (unsigned short*)(ws + off);  // bf16
  off += (size_t)MROWS * QKV_OUT * 4;  // region kept 75.5 MB (bf16 uses first 37.7)
  unsigned short* h_bf = (unsigned short*)(ws + off);
  off += (size_t)MROWS * HIDDEN * 2;  // 33.6 MB (reused as Qb after QKV GEMM)
  unsigned short* wq_bf = (unsigned short*)(ws + off);
  off += (size_t)QKV_OUT * HIDDEN * 2;  // 37.7 MB (reused as Om after QKV GEMM)
  unsigned short* wd_bf = (unsigned short*)(ws + off);
  off += (size_t)HIDDEN * HIDDEN * 2;  // 33.6 MB
  unsigned short* Kb = (unsigned short*)(ws + off);
  off += (size_t)BATCH * NKV * SLEN * HD * 2;  // 2 MB
  unsigned short* Vt = (unsigned short*)(ws + off);
  off += (size_t)BATCH * NKV * SLEN * HD * 2;  // 2 MB
  unsigned short* Qb = h_bf;                        // alias: h_bf dead after QKV GEMM
  unsigned short* ctx_bf = mixed;                   // alias: mixed dead after prep
  unsigned short* Om = wq_bf;                       // alias: wq_bf dead after QKV GEMM
  float* Ml = (float*)((char*)mixed + 36 * 1024 * 1024);  // mixed-region tail, past ctx_bf

  cvt3_f32_bf16<<<2048, 256, 0, stream>>>(hidden, h_bf, MROWS * HIDDEN / 4,
                                          w_qkv, wq_bf, QKV_OUT * HIDDEN / 4,
                                          w_dense, wd_bf, HIDDEN * HIDDEN / 4);

  gemm_bf16_mfma<<<dim3(QKV_OUT / 128, MROWS / 128), 256, 0, stream>>>(
      h_bf, wq_bf, b_qkv, mixed, MROWS, QKV_OUT, HIDDEN, 1);

  prep_qkv<<<MROWS, 256, 0, stream>>>(mixed, positions, Qb, Kb, Vt);

  flash_mfma<<<dim3(24, NH, BATCH), 512, 0, stream>>>(Qb, Kb, Vt, ctx_bf, Om, Ml);

  combine_partials<<<1024, 256, 0, stream>>>(Om, Ml, ctx_bf);

  gemm_bf16_mfma<<<dim3(HIDDEN / 128, MROWS / 128), 256, 0, stream>>>(
      ctx_bf, wd_bf, nullptr, out, MROWS, HIDDEN, HIDDEN, 0);
}

// Round 13
// 609.249 us; speedup vs baseline: 1.5498x; 1.0526x over previous
//
#include <hip/hip_runtime.h>

// ---------------- types ----------------
typedef float f32x4 __attribute__((ext_vector_type(4)));
typedef __bf16 bf16x8 __attribute__((ext_vector_type(8)));
typedef unsigned short u16x4 __attribute__((ext_vector_type(4)));
typedef unsigned short u16x8 __attribute__((ext_vector_type(8)));

#define HIDDEN 4096
#define NH 32
#define NKV 2
#define HD 128
#define SLEN 2048
#define BATCH 2
#define QKV_OUT 4608  // NH*HD + 2*NKV*HD
#define MROWS 4096    // BATCH*SLEN
#define ATT_SCALE 0.08838834764831845f  // 128^-0.5 (folded into Q at prep)
#define KCHUNK 1024                     // split-K chunk (16 steps of 64)

// fp32 -> bf16 (RNE) bit pattern
__device__ __forceinline__ unsigned short f2bf(float f) {
  unsigned int u = __float_as_uint(f);
  u += 0x7fffu + ((u >> 16) & 1u);
  return (unsigned short)(u >> 16);
}

__device__ __forceinline__ float bf2f(unsigned short s) {
  return __uint_as_float((unsigned int)s << 16);
}

__device__ __forceinline__ void gload16(const void* g, void* l) {
  __builtin_amdgcn_global_load_lds((const __attribute__((address_space(1))) void*)g,
                                   (__attribute__((address_space(3))) void*)l, 16, 0, 0);
}

// ---------------- fp32 -> bf16 convert (3 buffers fused, one launch) ----------------
__global__ __launch_bounds__(256) void cvt3_f32_bf16(
    const float* __restrict__ s0, unsigned short* __restrict__ d0, int n0,
    const float* __restrict__ s1, unsigned short* __restrict__ d1, int n1,
    const float* __restrict__ s2, unsigned short* __restrict__ d2, int n2) {
  const int ntot = n0 + n1 + n2;
  const int stride = gridDim.x * blockDim.x;
  for (int i = blockIdx.x * blockDim.x + threadIdx.x; i < ntot; i += stride) {
    const float* src;
    unsigned short* dst;
    int j = i;
    if (j < n0) { src = s0; dst = d0; }
    else if (j < n0 + n1) { j -= n0; src = s1; dst = d1; }
    else { j -= n0 + n1; src = s2; dst = d2; }
    float4 v = reinterpret_cast<const float4*>(src)[j];
    u16x4 o;
    o[0] = f2bf(v.x); o[1] = f2bf(v.y); o[2] = f2bf(v.z); o[3] = f2bf(v.w);
    reinterpret_cast<u16x4*>(dst)[j] = o;
  }
}

// ---------------- bf16 MFMA GEMM v3: 128x256 tile, 8 waves, per-wave 64x64 ----------------
// r12-flash lever applied to the GEMM: same proven r8 two-barrier schedule + LDS
// layout, repartitioned to 512 threads / 8 waves (2M x 4N) with HALF the per-wave
// accumulator state (64 VGPR) -> ~2x waves/CU for latency hiding. Read efficiency
// unchanged (8 ds_read_b128 -> 16 MFMA). Half the blocks -> less B re-streaming.
__global__ __launch_bounds__(512) void gemm_bf16_mfma(
    const unsigned short* __restrict__ A, const unsigned short* __restrict__ B,
    const float* __restrict__ bias, void* __restrict__ Cout, int M, int N, int K,
    int c_bf16) {
  __shared__ unsigned short as_[128 * 32];  // 8 KB
  __shared__ unsigned short bs_[256 * 32];  // 16 KB
  const int tid = threadIdx.x;
  const int wave = tid >> 6;
  const int lane = tid & 63;
  const int lr = lane & 15, lg = lane >> 4;
  const int m0 = blockIdx.y * 128;
  const int n0 = blockIdx.x * 256;
  const int wm = (wave >> 2) * 64;  // 2 wave-rows
  const int wn = (wave & 3) * 64;   // 4 wave-cols

  f32x4 acc[4][4] = {};

  // staging: thread t covers row t>>2, col (t&3)*8; wave w's 64 lanes = rows
  // w*16..w*16+15 = 1024B contiguous (global_load_lds linear-dest rule).
  const int srow = tid >> 2;
  const int scol = (tid & 3) * 8;
  unsigned short* lA = as_ + wave * 512;
  unsigned short* lB0 = bs_ + wave * 512;
  unsigned short* lB1 = bs_ + 128 * 32 + wave * 512;

  const int nk = K >> 5;
  for (int kt = 0; kt < nk; ++kt) {
    const int kb = kt << 5;
    __syncthreads();
    gload16(A + (size_t)(m0 + srow) * K + kb + scol, lA);
    gload16(B + (size_t)(n0 + srow) * K + kb + scol, lB0);
    gload16(B + (size_t)(n0 + 128 + srow) * K + kb + scol, lB1);
    __syncthreads();

    bf16x8 aF[4], bF[4];
#pragma unroll
    for (int m4 = 0; m4 < 4; ++m4)
      aF[m4] = *reinterpret_cast<const bf16x8*>(
          &as_[(wm + m4 * 16 + lr) * 32 + lg * 8]);
#pragma unroll
    for (int n4 = 0; n4 < 4; ++n4)
      bF[n4] = *reinterpret_cast<const bf16x8*>(
          &bs_[(wn + n4 * 16 + lr) * 32 + lg * 8]);
#pragma unroll
    for (int m4 = 0; m4 < 4; ++m4)
#pragma unroll
      for (int n4 = 0; n4 < 4; ++n4)
        acc[m4][n4] =
            __builtin_amdgcn_mfma_f32_16x16x32_bf16(aF[m4], bF[n4], acc[m4][n4], 0, 0, 0);
  }

  // epilogue: C/D layout col=lane&15, row=(lane>>4)*4+reg
#pragma unroll
  for (int m4 = 0; m4 < 4; ++m4) {
#pragma unroll
    for (int n4 = 0; n4 < 4; ++n4) {
      const int col = n0 + wn + n4 * 16 + lr;
      const float bv = bias ? bias[col] : 0.0f;
      if (c_bf16) {
        unsigned short* C = (unsigned short*)Cout;
#pragma unroll
        for (int r = 0; r < 4; ++r) {
          const int row = m0 + wm + m4 * 16 + lg * 4 + r;
          C[(size_t)row * N + col] = f2bf(acc[m4][n4][r] + bv);
        }
      } else {
        float* C = (float*)Cout;
#pragma unroll
        for (int r = 0; r < 4; ++r) {
          const int row = m0 + wm + m4 * 16 + lg * 4 + r;
          C[(size_t)row * N + col] = acc[m4][n4][r] + bv;
        }
      }
    }
  }
}

// ---------------- prep: RoPE (fp32 trig) on bf16 mixed + scale-fold + head-major ----------------
__global__ __launch_bounds__(256) void prep_qkv(const unsigned short* __restrict__ mixed,
                                                const int* __restrict__ positions,
                                                unsigned short* __restrict__ Qb,
                                                unsigned short* __restrict__ Kb,
                                                unsigned short* __restrict__ Vt) {
  const int m = blockIdx.x;
  const int b = m >> 11, s = m & 2047;
  const float pos = (float)positions[m];
  const int dp = threadIdx.x & 63;  // pair index within head (d = 2*dp)
  const bool rope_lane = (dp < 32);
  float sn = 0.0f, cs = 1.0f;
  if (rope_lane) {
    const float inv = __expf(-(float)dp * 0.28782313662425572f);  // 10000^(-dp/32)
    sincosf(pos * inv, &sn, &cs);
  }
  const unsigned int* row =
      reinterpret_cast<const unsigned int*>(mixed + (size_t)m * QKV_OUT);
#pragma unroll
  for (int it = 0; it < 9; ++it) {
    const int p = it * 256 + threadIdx.x;  // pair index, 2304 total
    const int col = p * 2;
    const unsigned int pk = row[p];
    float r1 = bf2f((unsigned short)(pk & 0xffffu));
    float r2 = bf2f((unsigned short)(pk >> 16));
    const int d = col & 127;
    const bool is_v = (col >= NH * HD + NKV * HD);
    if (rope_lane && !is_v) {
      const float x1 = r1, x2 = r2;
      r1 = x1 * cs - x2 * sn;
      r2 = x1 * sn + x2 * cs;
    }
    if (col < NH * HD) {  // q: fold attention scale
      r1 *= ATT_SCALE;
      r2 *= ATT_SCALE;
      const int h = col >> 7;
      const unsigned int packed = (unsigned int)f2bf(r1) | ((unsigned int)f2bf(r2) << 16);
      *reinterpret_cast<unsigned int*>(
          &Qb[((size_t)(b * NH + h) * SLEN + s) * HD + d]) = packed;
    } else if (!is_v) {
      const int kv = (col - NH * HD) >> 7;
      const unsigned int packed = (unsigned int)f2bf(r1) | ((unsigned int)f2bf(r2) << 16);
      *reinterpret_cast<unsigned int*>(
          &Kb[((size_t)(b * NKV + kv) * SLEN + s) * HD + d]) = packed;
    } else {
      const int kv = (col - NH * HD - NKV * HD) >> 7;
      unsigned short* vb = Vt + ((size_t)(b * NKV + kv) * HD) * SLEN + s;
      vb[(size_t)d * SLEN] = f2bf(r1);
      vb[(size_t)(d + 1) * SLEN] = f2bf(r2);
    }
  }
}

// ---------------- bf16 MFMA flash attention v10 (r12 verbatim — proven) ----------------
__global__ __launch_bounds__(512) void flash_mfma(const unsigned short* __restrict__ Qb,
                                                  const unsigned short* __restrict__ Kb,
                                                  const unsigned short* __restrict__ Vt,
                                                  unsigned short* __restrict__ ctx,
                                                  unsigned short* __restrict__ Om,
                                                  float* __restrict__ Ml) {
  __shared__ unsigned short Ks[2][64 * 128];  // [key][d] swizzled, 2x16KB
  __shared__ unsigned short Vs[128 * 64];     // [d][key] swizzled, 16KB
  __shared__ unsigned short Ps[8][16 * 64];   // wave-private P, 8x2KB

  const int tid = threadIdx.x;
  const int wave = tid >> 6, lane = tid & 63;
  const int lr = lane & 15, lg = lane >> 4;

  // decode (qt, chunk), heavy blocks first
  const int i = blockIdx.x;
  int qt, c;
  if (i < 8) { qt = 15 - i; c = 0; }            // qt 15..8, chunk 0 (16 steps)
  else if (i < 16) { qt = 23 - i; c = 1; }      // qt 15..8, chunk 1
  else { qt = 23 - i; c = 0; }                  // qt 7..0, single chunk
  const int h = blockIdx.y, b = blockIdx.z;
  const int kv = h >> 4;  // G = 16
  const int q0 = qt * 128;
  const int s_begin = c * KCHUNK;
  const int s_end = min(KCHUNK * (c + 1), q0 + 128);
  const int nkt = (s_end - s_begin) >> 6;
  const bool single = (c == 0) && (s_end == q0 + 128);
  const int qbw = q0 + wave * 16;  // this wave's 16-q group

  const unsigned short* Kbase = Kb + (size_t)(b * NKV + kv) * SLEN * HD;
  const unsigned short* Vbase = Vt + (size_t)(b * NKV + kv) * HD * SLEN;

  // Q B-fragments (col = q = lr, k = lg*8 + ks*32); pre-scaled
  bf16x8 bQ[4];
  {
    const unsigned short* qp =
        Qb + ((size_t)(b * NH + h) * SLEN + qbw + lr) * HD;
#pragma unroll
    for (int ks = 0; ks < 4; ++ks)
      bQ[ks] = *reinterpret_cast<const bf16x8*>(qp + lg * 8 + ks * 32);
  }

  f32x4 accO[8] = {};
  float mi = -1e30f, li = 0.0f;

  const int vrow_off = lane >> 3, vchunk = lane & 7;
#define STAGE_K(cb, t)                                                                  \
  {                                                                                     \
    const int ss = s_begin + (t) * 64;                                                  \
    _Pragma("unroll") for (int si = 0; si < 2; ++si) {                                  \
      const int krow = wave * 8 + si * 4 + lg;                                          \
      gload16(Kbase + (size_t)(ss + krow) * HD + ((lr ^ (krow & 7)) << 3),              \
              &Ks[cb][(wave * 8 + si * 4) * 128]);                                      \
    }                                                                                   \
  }
#define STAGE_V(t)                                                                      \
  {                                                                                     \
    const int ss = s_begin + (t) * 64;                                                  \
    _Pragma("unroll") for (int si = 0; si < 2; ++si) {                                  \
      const int drow = wave * 16 + si * 8 + vrow_off;                                   \
      gload16(Vbase + (size_t)drow * SLEN + ss + ((vchunk ^ (drow & 7)) << 3),          \
              &Vs[(wave * 16 + si * 8) * 64]);                                          \
    }                                                                                   \
  }

  STAGE_K(0, 0);
  __syncthreads();  // K0 ready

  unsigned short* Pw = Ps[wave];

  for (int kt = 0; kt < nkt; ++kt) {
    const int cur = kt & 1;
    const int s0 = s_begin + kt * 64;
    STAGE_V(kt);                                 // V for THIS step (ready at mid barrier)
    if (kt + 1 < nkt) STAGE_K(cur ^ 1, kt + 1);  // K prefetch for next step
    const bool part = (s0 < qbw + 16);

    f32x4 accS[4] = {};
    if (part) {
      bf16x8 aK[4][4];
#pragma unroll
      for (int kb = 0; kb < 4; ++kb)
#pragma unroll
        for (int ks = 0; ks < 4; ++ks)
          aK[kb][ks] = *reinterpret_cast<const bf16x8*>(
              &Ks[cur][(kb * 16 + lr) * 128 + (((ks * 4 + lg) ^ (lr & 7)) << 3)]);
#pragma unroll
      for (int kb = 0; kb < 4; ++kb)
#pragma unroll
        for (int ks = 0; ks < 4; ++ks)
          accS[kb] = __builtin_amdgcn_mfma_f32_16x16x32_bf16(aK[kb][ks], bQ[ks], accS[kb], 0, 0, 0);
    }

    __syncthreads();  // mid: V staged + QK reads of Ks[cur] done across waves

    if (part) {
      // ---- lane-local online softmax (one q per lane) ----
      const int qrow = qbw + lr;
      float v[16];
#pragma unroll
      for (int kb = 0; kb < 4; ++kb)
#pragma unroll
        for (int r = 0; r < 4; ++r) v[kb * 4 + r] = accS[kb][r];
      if (s0 + 63 > qbw) {  // mask if last key can exceed group's FIRST row
#pragma unroll
        for (int kb = 0; kb < 4; ++kb)
#pragma unroll
          for (int r = 0; r < 4; ++r)
            if (s0 + kb * 16 + lg * 4 + r > qrow) v[kb * 4 + r] = -1e30f;
      }
      float m16 = v[0];
#pragma unroll
      for (int i2 = 1; i2 < 16; ++i2) m16 = fmaxf(m16, v[i2]);
      m16 = fmaxf(m16, __shfl_xor(m16, 16));
      m16 = fmaxf(m16, __shfl_xor(m16, 32));
      const float mnew = fmaxf(mi, m16);
      const float cf = __expf(mi - mnew);
      mi = mnew;
      float rs = 0.0f;
#pragma unroll
      for (int i2 = 0; i2 < 16; ++i2) {
        const float p = __expf(v[i2] - mnew);
        v[i2] = p;
        rs += p;
      }
      rs += __shfl_xor(rs, 16);
      rs += __shfl_xor(rs, 32);
      li = li * cf + rs;
#pragma unroll
      for (int n8 = 0; n8 < 8; ++n8) accO[n8] *= cf;
#pragma unroll
      for (int kb = 0; kb < 4; ++kb) {
        const int slot = (kb * 2 + (lg >> 1)) ^ (lr & 7);
        u16x4 pk;
        pk[0] = f2bf(v[kb * 4 + 0]); pk[1] = f2bf(v[kb * 4 + 1]);
        pk[2] = f2bf(v[kb * 4 + 2]); pk[3] = f2bf(v[kb * 4 + 3]);
        *reinterpret_cast<u16x4*>(&Pw[lr * 64 + slot * 8 + (lg & 1) * 4]) = pk;
      }

      // ---- O^T += V^T · P^T ----
      bf16x8 pa[2];
#pragma unroll
      for (int ks = 0; ks < 2; ++ks)
        pa[ks] = *reinterpret_cast<const bf16x8*>(
            &Pw[lr * 64 + (((ks * 4 + lg) ^ (lr & 7)) << 3)]);
#pragma unroll
      for (int ks = 0; ks < 2; ++ks) {
#pragma unroll
        for (int n8 = 0; n8 < 8; ++n8) {
          bf16x8 aV = *reinterpret_cast<const bf16x8*>(
              &Vs[(n8 * 16 + lr) * 64 + (((ks * 4 + lg) ^ (lr & 7)) << 3)]);
          accO[n8] = __builtin_amdgcn_mfma_f32_16x16x32_bf16(aV, pa[ks], accO[n8], 0, 0, 0);
        }
      }
    }

    __syncthreads();  // bottom: drains prefetch; orders Vs/Ks reuse
  }
#undef STAGE_K
#undef STAGE_V

  if (single) {
    const float inv = 1.0f / li;
    unsigned short* orow =
        ctx + (size_t)(b * SLEN + qbw + lr) * HIDDEN + h * HD + lg * 4;
#pragma unroll
    for (int n8 = 0; n8 < 8; ++n8) {
      u16x4 o;
#pragma unroll
      for (int r = 0; r < 4; ++r) o[r] = f2bf(accO[n8][r] * inv);
      *reinterpret_cast<u16x4*>(orow + n8 * 16) = o;
    }
  } else {
    const int row1k = qbw + lr - 1024;
    const size_t pbase = (size_t)((b * NH + h) * 2 + c) * 1024 + row1k;
    if (lg == 0) {
      Ml[pbase * 2] = mi;
      Ml[pbase * 2 + 1] = li;
    }
    unsigned short* prow = Om + pbase * 128 + lg * 4;
#pragma unroll
    for (int n8 = 0; n8 < 8; ++n8) {
      u16x4 o;
#pragma unroll
      for (int r = 0; r < 4; ++r) o[r] = f2bf(accO[n8][r]);
      *reinterpret_cast<u16x4*>(prow + n8 * 16) = o;
    }
  }
}

// ---------------- combine the two split-K partials (rows 1024..2047 per (b,h)) ----------------
__global__ __launch_bounds__(256) void combine_partials(
    const unsigned short* __restrict__ Om, const float* __restrict__ Ml,
    unsigned short* __restrict__ ctx) {
  const int g = blockIdx.x * 64 + (threadIdx.x >> 2);  // row id, 0..65535
  const int p = threadIdx.x & 3;                       // dim quarter (32 dims)
  const int row1k = g & 1023;
  const int h = (g >> 10) & 31;
  const int b = g >> 15;
  const size_t base0 = (size_t)((b * NH + h) * 2 + 0) * 1024 + row1k;
  const size_t base1 = (size_t)((b * NH + h) * 2 + 1) * 1024 + row1k;
  const float m0 = Ml[base0 * 2], l0 = Ml[base0 * 2 + 1];
  const float m1 = Ml[base1 * 2], l1 = Ml[base1 * 2 + 1];
  const float mx = fmaxf(m0, m1);
  const float w0 = __expf(m0 - mx), w1 = __expf(m1 - mx);
  const float inv = 1.0f / (w0 * l0 + w1 * l1);
  const unsigned short* n0 = Om + base0 * 128 + p * 32;
  const unsigned short* n1 = Om + base1 * 128 + p * 32;
  unsigned short* orow =
      ctx + (size_t)(b * SLEN + 1024 + row1k) * HIDDEN + h * HD + p * 32;
#pragma unroll
  for (int cch = 0; cch < 4; ++cch) {
    u16x8 a = *reinterpret_cast<const u16x8*>(n0 + cch * 8);
    u16x8 d = *reinterpret_cast<const u16x8*>(n1 + cch * 8);
    u16x8 o;
#pragma unroll
    for (int j = 0; j < 8; ++j)
      o[j] = f2bf((w0 * bf2f(a[j]) + w1 * bf2f(d[j])) * inv);
    *reinterpret_cast<u16x8*>(orow + cch * 8) = o;
  }
}

// ---------------- launch ----------------
extern "C" void kernel_launch(void* const* d_in, const int* in_sizes, int n_in,
                              void* d_out, int out_size, void* d_ws, size_t ws_size,
                              hipStream_t stream) {
  const int* positions = (const int*)d_in[0];
  const float* hidden = (const float*)d_in[1];
  const float* w_qkv = (const float*)d_in[2];
  const float* b_qkv = (const float*)d_in[3];
  const float* w_dense = (const float*)d_in[4];
  float* out = (float*)d_out;

  char* ws = (char*)d_ws;
  size_t off = 0;
  unsigned short* mixed = (unsigned short*)(ws + off);  // bf16
  off += (size_t)MROWS * QKV_OUT * 4;  // region kept 75.5 MB (bf16 uses first 37.7)
  unsigned short* h_bf = (unsigned short*)(ws + off);
  off += (size_t)MROWS * HIDDEN * 2;  // 33.6 MB (reused as Qb after QKV GEMM)
  unsigned short* wq_bf = (unsigned short*)(ws + off);
  off += (size_t)QKV_OUT * HIDDEN * 2;  // 37.7 MB (reused as Om after QKV GEMM)
  unsigned short* wd_bf = (unsigned short*)(ws + off);
  off += (size_t)HIDDEN * HIDDEN * 2;  // 33.6 MB
  unsigned short* Kb = (unsigned short*)(ws + off);
  off += (size_t)BATCH * NKV * SLEN * HD * 2;  // 2 MB
  unsigned short* Vt = (unsigned short*)(ws + off);
  off += (size_t)BATCH * NKV * SLEN * HD * 2;  // 2 MB
  unsigned short* Qb = h_bf;                        // alias: h_bf dead after QKV GEMM
  unsigned short* ctx_bf = mixed;                   // alias: mixed dead after prep
  unsigned short* Om = wq_bf;                       // alias: wq_bf dead after QKV GEMM
  float* Ml = (float*)((char*)mixed + 36 * 1024 * 1024);  // mixed-region tail, past ctx_bf

  cvt3_f32_bf16<<<2048, 256, 0, stream>>>(hidden, h_bf, MROWS * HIDDEN / 4,
                                          w_qkv, wq_bf, QKV_OUT * HIDDEN / 4,
                                          w_dense, wd_bf, HIDDEN * HIDDEN / 4);

  // QKV: tile 128x256 -> grid (4608/256, 4096/128) = (18, 32)
  gemm_bf16_mfma<<<dim3(QKV_OUT / 256, MROWS / 128), 512, 0, stream>>>(
      h_bf, wq_bf, b_qkv, mixed, MROWS, QKV_OUT, HIDDEN, 1);

  prep_qkv<<<MROWS, 256, 0, stream>>>(mixed, positions, Qb, Kb, Vt);

  flash_mfma<<<dim3(24, NH, BATCH), 512, 0, stream>>>(Qb, Kb, Vt, ctx_bf, Om, Ml);

  combine_partials<<<1024, 256, 0, stream>>>(Om, Ml, ctx_bf);

  // dense: grid (4096/256, 4096/128) = (16, 32)
  gemm_bf16_mfma<<<dim3(HIDDEN / 256, MROWS / 128), 512, 0, stream>>>(
      ctx_bf, wd_bf, nullptr, out, MROWS, HIDDEN, HIDDEN, 0);
}

// Round 14
// 529.364 us; speedup vs baseline: 1.7837x; 1.1509x over previous
//
#include <hip/hip_runtime.h>

// ---------------- types ----------------
typedef float f32x4 __attribute__((ext_vector_type(4)));
typedef __bf16 bf16x8 __attribute__((ext_vector_type(8)));
typedef unsigned short u16x4 __attribute__((ext_vector_type(4)));
typedef unsigned short u16x8 __attribute__((ext_vector_type(8)));

#define HIDDEN 4096
#define NH 32
#define NKV 2
#define HD 128
#define SLEN 2048
#define BATCH 2
#define QKV_OUT 4608  // NH*HD + 2*NKV*HD
#define MROWS 4096    // BATCH*SLEN
#define ATT_SCALE 0.08838834764831845f  // 128^-0.5
#define KCHUNK 1024                     // flash split-K chunk

// fp32 -> bf16 (RNE) bit pattern
__device__ __forceinline__ unsigned short f2bf(float f) {
  unsigned int u = __float_as_uint(f);
  u += 0x7fffu + ((u >> 16) & 1u);
  return (unsigned short)(u >> 16);
}

__device__ __forceinline__ float bf2f(unsigned short s) {
  return __uint_as_float((unsigned int)s << 16);
}

__device__ __forceinline__ void gload16(const void* g, void* l) {
  __builtin_amdgcn_global_load_lds((const __attribute__((address_space(1))) void*)g,
                                   (__attribute__((address_space(3))) void*)l, 16, 0, 0);
}

// ---------------- fp32 -> bf16 convert (3 buffers fused) ----------------
__global__ __launch_bounds__(256) void cvt3_f32_bf16(
    const float* __restrict__ s0, unsigned short* __restrict__ d0, int n0,
    const float* __restrict__ s1, unsigned short* __restrict__ d1, int n1,
    const float* __restrict__ s2, unsigned short* __restrict__ d2, int n2) {
  const int ntot = n0 + n1 + n2;
  const int stride = gridDim.x * blockDim.x;
  for (int i = blockIdx.x * blockDim.x + threadIdx.x; i < ntot; i += stride) {
    const float* src;
    unsigned short* dst;
    int j = i;
    if (j < n0) { src = s0; dst = d0; }
    else if (j < n0 + n1) { j -= n0; src = s1; dst = d1; }
    else { j -= n0 + n1; src = s2; dst = d2; }
    float4 v = reinterpret_cast<const float4*>(src)[j];
    u16x4 o;
    o[0] = f2bf(v.x); o[1] = f2bf(v.y); o[2] = f2bf(v.z); o[3] = f2bf(v.w);
    reinterpret_cast<u16x4*>(dst)[j] = o;
  }
}

// ---------------- trig table: tab[p][j] = (cos, sin)(p * 10000^(-j/32)) ----------------
__global__ __launch_bounds__(256) void build_trig(float2* __restrict__ tab) {
  const int idx = blockIdx.x * 256 + threadIdx.x;  // 65536 entries
  const int p = idx >> 5, j = idx & 31;
  const float inv = __expf(-(float)j * 0.28782313662425572f);
  float sn, cs;
  sincosf((float)p * inv, &sn, &cs);
  tab[idx] = make_float2(cs, sn);
}

// ---------------- bf16 MFMA GEMM v4: 128x256, 8 waves, BK=64, XOR-swizzled LDS ----------------
// BK=64 halves barrier-drains (64 steps); chunk^(row&7) swizzle (T2, source-side per
// rule #21) kills the [row][stride] bank conflicts. mode 0: fp32 C. mode 2: fused
// QKV epilogue (bias + RoPE-from-table on fp32 acc + scale-fold + head-major Q/K/V^T).
__global__ __launch_bounds__(512) void gemm_bf16_mfma(
    const unsigned short* __restrict__ A, const unsigned short* __restrict__ B,
    const float* __restrict__ bias, void* __restrict__ Cout, int M, int N, int K,
    int mode, const float2* __restrict__ tab, const int* __restrict__ positions,
    unsigned short* __restrict__ Qb, unsigned short* __restrict__ Kb,
    unsigned short* __restrict__ Vt) {
  __shared__ unsigned short as_[128 * 64];  // 16 KB
  __shared__ unsigned short bs_[256 * 64];  // 32 KB  (48 KB -> 3 blocks/CU)
  const int tid = threadIdx.x;
  const int wave = tid >> 6;
  const int lane = tid & 63;
  const int lr = lane & 15, lg = lane >> 4;
  const int m0 = blockIdx.y * 128;
  const int n0 = blockIdx.x * 256;
  const int wm = (wave >> 2) * 64;
  const int wn = (wave & 3) * 64;

  f32x4 acc[4][4] = {};

  // staging: thread t -> row t>>3 (per 64-row set), chunk t&7; source chunk
  // pre-swizzled by row&7 so LDS linear dest + swizzled read agree (rule #21).
  const int srow8 = tid >> 3;                        // 0..63
  const int schunk = (tid & 7) ^ (srow8 & 7);        // swizzled source chunk
  const int scol = schunk * 8;                       // elems
  unsigned short* lA = as_ + wave * 512;             // wave covers 8 rows = 1KB
  unsigned short* lB = bs_ + wave * 512;

  const int nk = K >> 6;
  for (int kt = 0; kt < nk; ++kt) {
    const int kb = kt << 6;
    __syncthreads();
    // A: 2 sets of 64 rows; B: 4 sets
    gload16(A + (size_t)(m0 + srow8) * K + kb + scol, lA);
    gload16(A + (size_t)(m0 + 64 + srow8) * K + kb + scol, lA + 4096);
    gload16(B + (size_t)(n0 + srow8) * K + kb + scol, lB);
    gload16(B + (size_t)(n0 + 64 + srow8) * K + kb + scol, lB + 4096);
    gload16(B + (size_t)(n0 + 128 + srow8) * K + kb + scol, lB + 8192);
    gload16(B + (size_t)(n0 + 192 + srow8) * K + kb + scol, lB + 12288);
    __syncthreads();

#pragma unroll
    for (int kk = 0; kk < 2; ++kk) {
      bf16x8 aF[4], bF[4];
#pragma unroll
      for (int m4 = 0; m4 < 4; ++m4)
        aF[m4] = *reinterpret_cast<const bf16x8*>(
            &as_[(wm + m4 * 16 + lr) * 64 + (((kk * 4 + lg) ^ (lr & 7)) << 3)]);
#pragma unroll
      for (int n4 = 0; n4 < 4; ++n4)
        bF[n4] = *reinterpret_cast<const bf16x8*>(
            &bs_[(wn + n4 * 16 + lr) * 64 + (((kk * 4 + lg) ^ (lr & 7)) << 3)]);
#pragma unroll
      for (int m4 = 0; m4 < 4; ++m4)
#pragma unroll
        for (int n4 = 0; n4 < 4; ++n4)
          acc[m4][n4] =
              __builtin_amdgcn_mfma_f32_16x16x32_bf16(aF[m4], bF[n4], acc[m4][n4], 0, 0, 0);
    }
  }

  // epilogue: C/D layout col=lr, row=lg*4+r
  if (mode == 0) {
    float* C = (float*)Cout;
#pragma unroll
    for (int m4 = 0; m4 < 4; ++m4) {
#pragma unroll
      for (int n4 = 0; n4 < 4; ++n4) {
        const int col = n0 + wn + n4 * 16 + lr;
        const float bv = bias ? bias[col] : 0.0f;
#pragma unroll
        for (int r = 0; r < 4; ++r) {
          const int row = m0 + wm + m4 * 16 + lg * 4 + r;
          C[(size_t)row * N + col] = acc[m4][n4][r] + bv;
        }
      }
    }
  } else {
    // mode 2: fused QKV epilogue. cols: [0,4096)=q, [4096,4352)=k, [4352,4608)=v.
#pragma unroll
    for (int m4 = 0; m4 < 4; ++m4) {
      const int rowb = m0 + wm + m4 * 16 + lg * 4;  // 4 rows, same batch (rowb%4==0)
      const int bb = rowb >> 11;
      const int ss = rowb & 2047;
      int pos[4];
#pragma unroll
      for (int r = 0; r < 4; ++r) pos[r] = positions[rowb + r];
#pragma unroll
      for (int n4 = 0; n4 < 4; ++n4) {
        const int col = n0 + wn + n4 * 16 + lr;
        const float bv = bias[col];
        float val[4];
#pragma unroll
        for (int r = 0; r < 4; ++r) val[r] = acc[m4][n4][r] + bv;
        const int d = col & 127;
        const bool isv = (col >= NH * HD + NKV * HD);
        const bool isq = (col < NH * HD);
        if (d < 64 && !isv) {  // RoPE (uniform over lane pairs: regions 128-aligned)
          const int j = d >> 1;
#pragma unroll
          for (int r = 0; r < 4; ++r) {
            const float2 t = tab[pos[r] * 32 + j];
            const float other = __shfl_xor(val[r], 1);
            val[r] = (col & 1) ? (other * t.y + val[r] * t.x)
                               : (val[r] * t.x - other * t.y);
          }
        }
        if (isq) {
          const int hh = col >> 7;
          unsigned short* q = Qb + ((size_t)(bb * NH + hh) * SLEN + ss) * HD + d;
#pragma unroll
          for (int r = 0; r < 4; ++r) q[(size_t)r * HD] = f2bf(val[r] * ATT_SCALE);
        } else if (!isv) {
          const int kvh = (col - NH * HD) >> 7;
          unsigned short* k = Kb + ((size_t)(bb * NKV + kvh) * SLEN + ss) * HD + d;
#pragma unroll
          for (int r = 0; r < 4; ++r) k[(size_t)r * HD] = f2bf(val[r]);
        } else {
          const int kvh = (col - NH * HD - NKV * HD) >> 7;
          u16x4 o;
#pragma unroll
          for (int r = 0; r < 4; ++r) o[r] = f2bf(val[r]);
          *reinterpret_cast<u16x4*>(
              &Vt[((size_t)(bb * NKV + kvh) * HD + d) * SLEN + ss]) = o;
        }
      }
    }
  }
}

// ---------------- bf16 MFMA flash attention v10 (r12/r13 verbatim — proven) ----------------
__global__ __launch_bounds__(512) void flash_mfma(const unsigned short* __restrict__ Qb,
                                                  const unsigned short* __restrict__ Kb,
                                                  const unsigned short* __restrict__ Vt,
                                                  unsigned short* __restrict__ ctx,
                                                  unsigned short* __restrict__ Om,
                                                  float* __restrict__ Ml) {
  __shared__ unsigned short Ks[2][64 * 128];  // [key][d] swizzled, 2x16KB
  __shared__ unsigned short Vs[128 * 64];     // [d][key] swizzled, 16KB
  __shared__ unsigned short Ps[8][16 * 64];   // wave-private P, 8x2KB

  const int tid = threadIdx.x;
  const int wave = tid >> 6, lane = tid & 63;
  const int lr = lane & 15, lg = lane >> 4;

  const int i = blockIdx.x;
  int qt, c;
  if (i < 8) { qt = 15 - i; c = 0; }
  else if (i < 16) { qt = 23 - i; c = 1; }
  else { qt = 23 - i; c = 0; }
  const int h = blockIdx.y, b = blockIdx.z;
  const int kv = h >> 4;  // G = 16
  const int q0 = qt * 128;
  const int s_begin = c * KCHUNK;
  const int s_end = min(KCHUNK * (c + 1), q0 + 128);
  const int nkt = (s_end - s_begin) >> 6;
  const bool single = (c == 0) && (s_end == q0 + 128);
  const int qbw = q0 + wave * 16;

  const unsigned short* Kbase = Kb + (size_t)(b * NKV + kv) * SLEN * HD;
  const unsigned short* Vbase = Vt + (size_t)(b * NKV + kv) * HD * SLEN;

  bf16x8 bQ[4];
  {
    const unsigned short* qp = Qb + ((size_t)(b * NH + h) * SLEN + qbw + lr) * HD;
#pragma unroll
    for (int ks = 0; ks < 4; ++ks)
      bQ[ks] = *reinterpret_cast<const bf16x8*>(qp + lg * 8 + ks * 32);
  }

  f32x4 accO[8] = {};
  float mi = -1e30f, li = 0.0f;

  const int vrow_off = lane >> 3, vchunk = lane & 7;
#define STAGE_K(cb, t)                                                                  \
  {                                                                                     \
    const int ss = s_begin + (t) * 64;                                                  \
    _Pragma("unroll") for (int si = 0; si < 2; ++si) {                                  \
      const int krow = wave * 8 + si * 4 + lg;                                          \
      gload16(Kbase + (size_t)(ss + krow) * HD + ((lr ^ (krow & 7)) << 3),              \
              &Ks[cb][(wave * 8 + si * 4) * 128]);                                      \
    }                                                                                   \
  }
#define STAGE_V(t)                                                                      \
  {                                                                                     \
    const int ss = s_begin + (t) * 64;                                                  \
    _Pragma("unroll") for (int si = 0; si < 2; ++si) {                                  \
      const int drow = wave * 16 + si * 8 + vrow_off;                                   \
      gload16(Vbase + (size_t)drow * SLEN + ss + ((vchunk ^ (drow & 7)) << 3),          \
              &Vs[(wave * 16 + si * 8) * 64]);                                          \
    }                                                                                   \
  }

  STAGE_K(0, 0);
  __syncthreads();

  unsigned short* Pw = Ps[wave];

  for (int kt = 0; kt < nkt; ++kt) {
    const int cur = kt & 1;
    const int s0 = s_begin + kt * 64;
    STAGE_V(kt);
    if (kt + 1 < nkt) STAGE_K(cur ^ 1, kt + 1);
    const bool part = (s0 < qbw + 16);

    f32x4 accS[4] = {};
    if (part) {
      bf16x8 aK[4][4];
#pragma unroll
      for (int kb = 0; kb < 4; ++kb)
#pragma unroll
        for (int ks = 0; ks < 4; ++ks)
          aK[kb][ks] = *reinterpret_cast<const bf16x8*>(
              &Ks[cur][(kb * 16 + lr) * 128 + (((ks * 4 + lg) ^ (lr & 7)) << 3)]);
#pragma unroll
      for (int kb = 0; kb < 4; ++kb)
#pragma unroll
        for (int ks = 0; ks < 4; ++ks)
          accS[kb] = __builtin_amdgcn_mfma_f32_16x16x32_bf16(aK[kb][ks], bQ[ks], accS[kb], 0, 0, 0);
    }

    __syncthreads();

    if (part) {
      const int qrow = qbw + lr;
      float v[16];
#pragma unroll
      for (int kb = 0; kb < 4; ++kb)
#pragma unroll
        for (int r = 0; r < 4; ++r) v[kb * 4 + r] = accS[kb][r];
      if (s0 + 63 > qbw) {
#pragma unroll
        for (int kb = 0; kb < 4; ++kb)
#pragma unroll
          for (int r = 0; r < 4; ++r)
            if (s0 + kb * 16 + lg * 4 + r > qrow) v[kb * 4 + r] = -1e30f;
      }
      float m16 = v[0];
#pragma unroll
      for (int i2 = 1; i2 < 16; ++i2) m16 = fmaxf(m16, v[i2]);
      m16 = fmaxf(m16, __shfl_xor(m16, 16));
      m16 = fmaxf(m16, __shfl_xor(m16, 32));
      const float mnew = fmaxf(mi, m16);
      const float cf = __expf(mi - mnew);
      mi = mnew;
      float rs = 0.0f;
#pragma unroll
      for (int i2 = 0; i2 < 16; ++i2) {
        const float p = __expf(v[i2] - mnew);
        v[i2] = p;
        rs += p;
      }
      rs += __shfl_xor(rs, 16);
      rs += __shfl_xor(rs, 32);
      li = li * cf + rs;
#pragma unroll
      for (int n8 = 0; n8 < 8; ++n8) accO[n8] *= cf;
#pragma unroll
      for (int kb = 0; kb < 4; ++kb) {
        const int slot = (kb * 2 + (lg >> 1)) ^ (lr & 7);
        u16x4 pk;
        pk[0] = f2bf(v[kb * 4 + 0]); pk[1] = f2bf(v[kb * 4 + 1]);
        pk[2] = f2bf(v[kb * 4 + 2]); pk[3] = f2bf(v[kb * 4 + 3]);
        *reinterpret_cast<u16x4*>(&Pw[lr * 64 + slot * 8 + (lg & 1) * 4]) = pk;
      }

      bf16x8 pa[2];
#pragma unroll
      for (int ks = 0; ks < 2; ++ks)
        pa[ks] = *reinterpret_cast<const bf16x8*>(
            &Pw[lr * 64 + (((ks * 4 + lg) ^ (lr & 7)) << 3)]);
#pragma unroll
      for (int ks = 0; ks < 2; ++ks) {
#pragma unroll
        for (int n8 = 0; n8 < 8; ++n8) {
          bf16x8 aV = *reinterpret_cast<const bf16x8*>(
              &Vs[(n8 * 16 + lr) * 64 + (((ks * 4 + lg) ^ (lr & 7)) << 3)]);
          accO[n8] = __builtin_amdgcn_mfma_f32_16x16x32_bf16(aV, pa[ks], accO[n8], 0, 0, 0);
        }
      }
    }

    __syncthreads();
  }
#undef STAGE_K
#undef STAGE_V

  if (single) {
    const float inv = 1.0f / li;
    unsigned short* orow =
        ctx + (size_t)(b * SLEN + qbw + lr) * HIDDEN + h * HD + lg * 4;
#pragma unroll
    for (int n8 = 0; n8 < 8; ++n8) {
      u16x4 o;
#pragma unroll
      for (int r = 0; r < 4; ++r) o[r] = f2bf(accO[n8][r] * inv);
      *reinterpret_cast<u16x4*>(orow + n8 * 16) = o;
    }
  } else {
    const int row1k = qbw + lr - 1024;
    const size_t pbase = (size_t)((b * NH + h) * 2 + c) * 1024 + row1k;
    if (lg == 0) {
      Ml[pbase * 2] = mi;
      Ml[pbase * 2 + 1] = li;
    }
    unsigned short* prow = Om + pbase * 128 + lg * 4;
#pragma unroll
    for (int n8 = 0; n8 < 8; ++n8) {
      u16x4 o;
#pragma unroll
      for (int r = 0; r < 4; ++r) o[r] = f2bf(accO[n8][r]);
      *reinterpret_cast<u16x4*>(prow + n8 * 16) = o;
    }
  }
}

// ---------------- combine the two split-K partials ----------------
__global__ __launch_bounds__(256) void combine_partials(
    const unsigned short* __restrict__ Om, const float* __restrict__ Ml,
    unsigned short* __restrict__ ctx) {
  const int g = blockIdx.x * 64 + (threadIdx.x >> 2);
  const int p = threadIdx.x & 3;
  const int row1k = g & 1023;
  const int h = (g >> 10) & 31;
  const int b = g >> 15;
  const size_t base0 = (size_t)((b * NH + h) * 2 + 0) * 1024 + row1k;
  const size_t base1 = (size_t)((b * NH + h) * 2 + 1) * 1024 + row1k;
  const float m0 = Ml[base0 * 2], l0 = Ml[base0 * 2 + 1];
  const float m1 = Ml[base1 * 2], l1 = Ml[base1 * 2 + 1];
  const float mx = fmaxf(m0, m1);
  const float w0 = __expf(m0 - mx), w1 = __expf(m1 - mx);
  const float inv = 1.0f / (w0 * l0 + w1 * l1);
  const unsigned short* n0 = Om + base0 * 128 + p * 32;
  const unsigned short* n1 = Om + base1 * 128 + p * 32;
  unsigned short* orow =
      ctx + (size_t)(b * SLEN + 1024 + row1k) * HIDDEN + h * HD + p * 32;
#pragma unroll
  for (int cch = 0; cch < 4; ++cch) {
    u16x8 a = *reinterpret_cast<const u16x8*>(n0 + cch * 8);
    u16x8 d = *reinterpret_cast<const u16x8*>(n1 + cch * 8);
    u16x8 o;
#pragma unroll
    for (int j = 0; j < 8; ++j)
      o[j] = f2bf((w0 * bf2f(a[j]) + w1 * bf2f(d[j])) * inv);
    *reinterpret_cast<u16x8*>(orow + cch * 8) = o;
  }
}

// ---------------- launch ----------------
extern "C" void kernel_launch(void* const* d_in, const int* in_sizes, int n_in,
                              void* d_out, int out_size, void* d_ws, size_t ws_size,
                              hipStream_t stream) {
  const int* positions = (const int*)d_in[0];
  const float* hidden = (const float*)d_in[1];
  const float* w_qkv = (const float*)d_in[2];
  const float* b_qkv = (const float*)d_in[3];
  const float* w_dense = (const float*)d_in[4];
  float* out = (float*)d_out;

  char* ws = (char*)d_ws;
  size_t off = 0;
  unsigned short* mixed = (unsigned short*)(ws + off);  // now only ctx_bf + Ml region
  off += (size_t)MROWS * QKV_OUT * 4;  // 75.5 MB
  unsigned short* h_bf = (unsigned short*)(ws + off);
  off += (size_t)MROWS * HIDDEN * 2;  // 33.6 MB (reused as Qb after QKV GEMM)
  unsigned short* wq_bf = (unsigned short*)(ws + off);
  off += (size_t)QKV_OUT * HIDDEN * 2;  // 37.7 MB (reused as Om)
  unsigned short* wd_bf = (unsigned short*)(ws + off);
  off += (size_t)HIDDEN * HIDDEN * 2;  // 33.6 MB
  unsigned short* Kb = (unsigned short*)(ws + off);
  off += (size_t)BATCH * NKV * SLEN * HD * 2;  // 2 MB
  unsigned short* Vt = (unsigned short*)(ws + off);
  off += (size_t)BATCH * NKV * SLEN * HD * 2;  // 2 MB
  float2* trig = (float2*)(ws + off);
  off += (size_t)2048 * 32 * 8;  // 512 KB
  unsigned short* Qb = h_bf;  // NOTE: QKV GEMM reads h_bf (A) and writes Qb — but Qb
  // aliases h_bf! Writes happen in the epilogue AFTER all A reads of that block, yet
  // OTHER blocks still read A. So Qb must NOT alias h_bf anymore. Use mixed instead:
  Qb = mixed;                                       // mixed region is free until ctx
  unsigned short* ctx_bf = mixed + (size_t)MROWS * HIDDEN;  // 33.6MB after Qb (fits 75.5)
  unsigned short* Om = wq_bf;                       // wq_bf dead after QKV GEMM
  float* Ml = (float*)(ws + off);
  off += (size_t)BATCH * NH * 2 * 1024 * 2 * 4;  // 1 MB

  cvt3_f32_bf16<<<2048, 256, 0, stream>>>(hidden, h_bf, MROWS * HIDDEN / 4,
                                          w_qkv, wq_bf, QKV_OUT * HIDDEN / 4,
                                          w_dense, wd_bf, HIDDEN * HIDDEN / 4);
  build_trig<<<256, 256, 0, stream>>>(trig);

  // QKV GEMM with fused bias+RoPE+layout epilogue (mode 2)
  gemm_bf16_mfma<<<dim3(QKV_OUT / 256, MROWS / 128), 512, 0, stream>>>(
      h_bf, wq_bf, b_qkv, nullptr, MROWS, QKV_OUT, HIDDEN, 2, trig, positions,
      Qb, Kb, Vt);

  flash_mfma<<<dim3(24, NH, BATCH), 512, 0, stream>>>(Qb, Kb, Vt, ctx_bf, Om, Ml);

  combine_partials<<<1024, 256, 0, stream>>>(Om, Ml, ctx_bf);

  // dense GEMM (mode 0, fp32 out)
  gemm_bf16_mfma<<<dim3(HIDDEN / 256, MROWS / 128), 512, 0, stream>>>(
      ctx_bf, wd_bf, nullptr, out, MROWS, HIDDEN, HIDDEN, 0, nullptr, nullptr,
      nullptr, nullptr, nullptr);
}